// Round 8
// baseline (735.073 us; speedup 1.0000x reference)
//
#include <hip/hip_runtime.h>
#include <cstddef>

#define LN_EPS 1e-5f

typedef unsigned short u16;
typedef short short8 __attribute__((ext_vector_type(8)));
typedef float f32x4 __attribute__((ext_vector_type(4)));

__device__ __forceinline__ u16 f2bf(float f) {
    unsigned int u = __float_as_uint(f);
    u = (u + 0x7FFFu + ((u >> 16) & 1u)) >> 16;
    return (u16)u;
}
__device__ __forceinline__ float bf2f(u16 h) {
    return __uint_as_float((unsigned int)h << 16);
}

// ---------------------------------------------------------------------------
// Multi-tensor fp32 -> bf16 convert (weights + inputs), one launch.
// ---------------------------------------------------------------------------
struct CvtDesc {
    const float* src[16];
    u16* dst[16];
    int n4[16];
};
__global__ __launch_bounds__(256) void cvt_multi(CvtDesc d) {
    const int t = blockIdx.x * 256 + threadIdx.x;
    const int i = blockIdx.y;
    if (t >= d.n4[i]) return;
    const float4 v = ((const float4*)d.src[i])[t];
    ushort4 o;
    o.x = f2bf(v.x); o.y = f2bf(v.y); o.z = f2bf(v.z); o.w = f2bf(v.w);
    ((ushort4*)d.dst[i])[t] = o;
}

// ---------------------------------------------------------------------------
// bf16 MFMA NT GEMM, BMxBN tile, 4 waves (2x2), BK=32, 16x16x32 MFMA.
// LDS rows padded to 40 u16; K-loop register-prefetches the next chunk.
// C = scale*(A@B^T + bias) + res1 + res2 (+relu). Outputs fp32 and/or bf16.
// Batched over grid.z: bz -> (b = bz&1, h = bz>>1) offsets for A/B/C.
// STATS: epilogue also emits per-row (max, sumexp) partials over this block's
// col-tile, computed from the bf16-ROUNDED stored values (so downstream exp
// reconstruction matches exactly). pstat layout: [bz][row][nx], nx=(N/BN)*2.
// ---------------------------------------------------------------------------
template<int BM, int BN, bool STATS>
__global__ __launch_bounds__(256) void mfma_gemm(
    const u16* __restrict__ A, int lda, int aOffB, int aOffH,
    const u16* __restrict__ B, int ldb, int bOffB, int bOffH,
    float* __restrict__ Cf, u16* __restrict__ Ch,
    int ldc, long cOffB, long cOffH,
    const float* __restrict__ bias,
    const float* __restrict__ res1, const float* __restrict__ res2,
    float scale, int relu, int K,
    float2* __restrict__ pstat, long statStride, int pstatLD)
{
    constexpr int MF = BM / 32;
    constexpr int NF = BN / 32;
    constexpr int MC = BM / 64;
    constexpr int NC = BN / 64;
    __shared__ u16 As[BM * 40];
    __shared__ u16 Bs[BN * 40];

    const int tid = threadIdx.x;
    const int wave = tid >> 6, lane = tid & 63;
    const int wm = wave >> 1, wn = wave & 1;
    const int m0 = blockIdx.y * BM, n0 = blockIdx.x * BN;
    const int bz = blockIdx.z, bb = bz & 1, hh = bz >> 1;
    const size_t aOff = (size_t)bb * aOffB + (size_t)hh * aOffH;
    const size_t bOff = (size_t)bb * bOffB + (size_t)hh * bOffH;
    const size_t cOff = (size_t)bb * cOffB + (size_t)hh * cOffH;

    f32x4 acc[MF][NF];
#pragma unroll
    for (int mf = 0; mf < MF; ++mf)
#pragma unroll
        for (int nf = 0; nf < NF; ++nf) acc[mf][nf] = (f32x4){0.f, 0.f, 0.f, 0.f};

    const int ar = tid >> 2, ac = (tid & 3) * 8;
    const int ml = lane & 15, kq = lane >> 4;

    short8 aN[MC], bN[NC];
#pragma unroll
    for (int c = 0; c < MC; ++c)
        aN[c] = *(const short8*)&A[aOff + (size_t)(m0 + ar + c * 64) * lda + ac];
#pragma unroll
    for (int c = 0; c < NC; ++c)
        bN[c] = *(const short8*)&B[bOff + (size_t)(n0 + ar + c * 64) * ldb + ac];

    for (int k0 = 0; k0 < K; k0 += 32) {
        short8 aS[MC], bS[NC];
#pragma unroll
        for (int c = 0; c < MC; ++c) aS[c] = aN[c];
#pragma unroll
        for (int c = 0; c < NC; ++c) bS[c] = bN[c];
        if (k0 + 32 < K) {
#pragma unroll
            for (int c = 0; c < MC; ++c)
                aN[c] = *(const short8*)&A[aOff + (size_t)(m0 + ar + c * 64) * lda + k0 + 32 + ac];
#pragma unroll
            for (int c = 0; c < NC; ++c)
                bN[c] = *(const short8*)&B[bOff + (size_t)(n0 + ar + c * 64) * ldb + k0 + 32 + ac];
        }
        __syncthreads();
#pragma unroll
        for (int c = 0; c < MC; ++c) *(short8*)&As[(ar + c * 64) * 40 + ac] = aS[c];
#pragma unroll
        for (int c = 0; c < NC; ++c) *(short8*)&Bs[(ar + c * 64) * 40 + ac] = bS[c];
        __syncthreads();

        short8 af[MF], bfr[NF];
#pragma unroll
        for (int mf = 0; mf < MF; ++mf)
            af[mf] = *(const short8*)&As[(wm * (BM / 2) + mf * 16 + ml) * 40 + kq * 8];
#pragma unroll
        for (int nf = 0; nf < NF; ++nf)
            bfr[nf] = *(const short8*)&Bs[(wn * (BN / 2) + nf * 16 + ml) * 40 + kq * 8];
#pragma unroll
        for (int mf = 0; mf < MF; ++mf)
#pragma unroll
            for (int nf = 0; nf < NF; ++nf)
                acc[mf][nf] = __builtin_amdgcn_mfma_f32_16x16x32_bf16(
                    af[mf], bfr[nf], acc[mf][nf], 0, 0, 0);
    }

    const int rq = lane >> 4;
#pragma unroll
    for (int mf = 0; mf < MF; ++mf)
#pragma unroll
        for (int nf = 0; nf < NF; ++nf) {
            const int col = n0 + wn * (BN / 2) + nf * 16 + ml;
            const float bv = bias ? bias[col] : 0.f;
#pragma unroll
            for (int r = 0; r < 4; ++r) {
                const int row = m0 + wm * (BM / 2) + mf * 16 + rq * 4 + r;
                float v = scale * (acc[mf][nf][r] + bv);
                const size_t idx = cOff + (size_t)row * ldc + col;
                if (res1) v += res1[idx];
                if (res2) v += res2[idx];
                if (relu) v = fmaxf(v, 0.f);
                if (Cf) Cf[idx] = v;
                if (Ch) Ch[idx] = f2bf(v);
            }
        }

    if (STATS) {
        // per-row (max, sumexp) over this block's BN/2 cols per wn half,
        // from bf16-rounded values; 16-lane shuffle reductions (rq preserved).
#pragma unroll
        for (int mf = 0; mf < MF; ++mf)
#pragma unroll
            for (int r = 0; r < 4; ++r) {
                float vals[NF];
                float lm = -1e30f;
#pragma unroll
                for (int nf = 0; nf < NF; ++nf) {
                    const float vr = bf2f(f2bf(scale * acc[mf][nf][r]));
                    vals[nf] = vr; lm = fmaxf(lm, vr);
                }
                lm = fmaxf(lm, __shfl_xor(lm, 1));
                lm = fmaxf(lm, __shfl_xor(lm, 2));
                lm = fmaxf(lm, __shfl_xor(lm, 4));
                lm = fmaxf(lm, __shfl_xor(lm, 8));
                float ls = 0.f;
#pragma unroll
                for (int nf = 0; nf < NF; ++nf) ls += __expf(vals[nf] - lm);
                ls += __shfl_xor(ls, 1);
                ls += __shfl_xor(ls, 2);
                ls += __shfl_xor(ls, 4);
                ls += __shfl_xor(ls, 8);
                if (ml == 0) {
                    const int row = m0 + wm * (BM / 2) + mf * 16 + rq * 4 + r;
                    pstat[(size_t)bz * statStride + (size_t)row * pstatLD
                          + blockIdx.x * 2 + wn] = make_float2(lm, ls);
                }
            }
    }
}

// ---------------------------------------------------------------------------
// Merge per-block stat partials -> stats[row] = (max, 1/sum). 1 thread/row.
// rows = 16*L; partials contiguous per row (nx of them).
// ---------------------------------------------------------------------------
__global__ __launch_bounds__(256) void merge_stats(
    const float2* __restrict__ pstat, float2* __restrict__ stats,
    int rows, int nx)
{
    const int r = blockIdx.x * 256 + threadIdx.x;
    if (r >= rows) return;
    const float2* p = pstat + (size_t)r * nx;
    float m = p[0].x, s = p[0].y;
    for (int j = 1; j < nx; ++j) {
        const float2 q = p[j];
        const float nm = fmaxf(m, q.x);
        s = s * __expf(m - nm) + q.y * __expf(q.x - nm);
        m = nm;
    }
    stats[r] = make_float2(m, 1.0f / s);
}

// ---------------------------------------------------------------------------
// Single-pass PV: 32(i) x 64(d) tile per block, one bh. Reads precomputed
// stats; exp(s-m)*inv applied at LDS staging; register prefetch; BK=32.
// att[(i*2+b)*512 + h*64 + d] (bf16).  vT: [bh][64][S].
// ---------------------------------------------------------------------------
__global__ __launch_bounds__(256) void pv2(
    const u16* __restrict__ P, const u16* __restrict__ vT,
    const float2* __restrict__ stats, u16* __restrict__ att, int L, int S)
{
    __shared__ u16 As[32 * 40];
    __shared__ u16 Bs[64 * 40];
    const int tid = threadIdx.x;
    const int wave = tid >> 6, lane = tid & 63;
    const int ml = lane & 15, rq = lane >> 4;
    const int i0 = blockIdx.x * 32;
    const int bz = blockIdx.y, bb = bz & 1, hh = bz >> 1;
    const u16* Pb = P + (size_t)bz * L * S + (size_t)i0 * S;
    const u16* Vb = vT + (size_t)bz * 64 * S;

    const int r = tid >> 2, ac = (tid & 3) * 8;   // B rows r=0..63; A uses r<32
    const bool doA = tid < 128;
    float mxv = 0.f, invv = 1.f;
    if (doA) {
        const float2 st = stats[(size_t)bz * L + i0 + r];
        mxv = st.x; invv = st.y;
    }

    f32x4 acc[2];
    acc[0] = (f32x4){0.f, 0.f, 0.f, 0.f};
    acc[1] = (f32x4){0.f, 0.f, 0.f, 0.f};

    short8 aN = {};
    if (doA) aN = *(const short8*)&Pb[(size_t)r * S + ac];
    short8 bN = *(const short8*)&Vb[(size_t)r * S + ac];

    for (int k0 = 0; k0 < S; k0 += 32) {
        short8 aS = {};
        const short8 bS = bN;
        if (doA) {
#pragma unroll
            for (int j = 0; j < 8; ++j)
                aS[j] = (short)f2bf(__expf(bf2f((u16)aN[j]) - mxv) * invv);
        }
        if (k0 + 32 < S) {
            if (doA) aN = *(const short8*)&Pb[(size_t)r * S + k0 + 32 + ac];
            bN = *(const short8*)&Vb[(size_t)r * S + k0 + 32 + ac];
        }
        __syncthreads();
        if (doA) *(short8*)&As[r * 40 + ac] = aS;
        *(short8*)&Bs[r * 40 + ac] = bS;
        __syncthreads();

        const short8 af0 = *(const short8*)&As[(ml) * 40 + rq * 8];
        const short8 af1 = *(const short8*)&As[(16 + ml) * 40 + rq * 8];
        const short8 bfr = *(const short8*)&Bs[(wave * 16 + ml) * 40 + rq * 8];
        acc[0] = __builtin_amdgcn_mfma_f32_16x16x32_bf16(af0, bfr, acc[0], 0, 0, 0);
        acc[1] = __builtin_amdgcn_mfma_f32_16x16x32_bf16(af1, bfr, acc[1], 0, 0, 0);
    }

#pragma unroll
    for (int mf = 0; mf < 2; ++mf)
#pragma unroll
        for (int rr = 0; rr < 4; ++rr) {
            const int i = i0 + mf * 16 + rq * 4 + rr;
            const int d = wave * 16 + ml;
            att[((size_t)i * 2 + bb) * 512 + hh * 64 + d] = f2bf(acc[mf][rr]);
        }
}

// ---------------------------------------------------------------------------
// One-time V transpose: vT[bh][d][s] = V[(s*2+b)*ldv + h*64 + d]  (bf16).
// ---------------------------------------------------------------------------
__global__ __launch_bounds__(256) void vtrans(
    const u16* __restrict__ V, int ldv, u16* __restrict__ vT, int S)
{
    __shared__ u16 Vs[64 * 72];
    const int tid = threadIdx.x;
    const int s0 = blockIdx.x * 64;
    const int bh = blockIdx.y, b = bh & 1, h = bh >> 1;

#pragma unroll
    for (int c = 0; c < 2; ++c) {
        const int idx = tid + c * 256;
        const int sr = idx >> 3, dc = (idx & 7) * 8;
        *(short8*)&Vs[sr * 72 + dc] =
            *(const short8*)&V[(size_t)((s0 + sr) * 2 + b) * ldv + h * 64 + dc];
    }
    __syncthreads();
#pragma unroll
    for (int c = 0; c < 2; ++c) {
        const int idx = tid + c * 256;
        const int dr = idx >> 3, sc = (idx & 7) * 8;
        short8 o;
#pragma unroll
        for (int j = 0; j < 8; ++j) o[j] = (short)Vs[(sc + j) * 72 + dr];
        *(short8*)&vT[(size_t)bh * 64 * S + (size_t)dr * S + s0 + sc] = o;
    }
}

// ---------------------------------------------------------------------------
// Fused: head-average of (stats-normalized) probs from RAW scores + second
// softmax -> fp32 out (1 or 2 copies). grid = 2*L, blockIdx.x = b*L + i.
// ---------------------------------------------------------------------------
__global__ __launch_bounds__(256) void avg_softmax_f(
    const u16* __restrict__ P, const float2* __restrict__ st, int L, int S,
    float* __restrict__ out1, float* __restrict__ out2)
{
    __shared__ float red[256];
    const int tid = threadIdx.x;
    const bool act = tid * 8 < S;
    const int b = blockIdx.x / L, i = blockIdx.x % L;
    const size_t LS = (size_t)L * S;

    float acc[8] = {};
    if (act) {
#pragma unroll
        for (int h = 0; h < 8; ++h) {
            const int bh = h * 2 + b;
            const float2 s = st[(size_t)bh * L + i];
            const short8 r8 = *(const short8*)&P[(size_t)bh * LS + (size_t)i * S + tid * 8];
#pragma unroll
            for (int j = 0; j < 8; ++j)
                acc[j] += __expf(bf2f((u16)r8[j]) - s.x) * s.y;
        }
#pragma unroll
        for (int j = 0; j < 8; ++j) acc[j] *= 0.125f;
    }
    float lmax = -1e30f;
    if (act) {
#pragma unroll
        for (int j = 0; j < 8; ++j) lmax = fmaxf(lmax, acc[j]);
    }
    red[tid] = lmax; __syncthreads();
    for (int s = 128; s; s >>= 1) {
        if (tid < s) red[tid] = fmaxf(red[tid], red[tid + s]);
        __syncthreads();
    }
    const float mx = red[0]; __syncthreads();
    float e[8];
    float ls = 0.f;
    if (act) {
#pragma unroll
        for (int j = 0; j < 8; ++j) { e[j] = __expf(acc[j] - mx); ls += e[j]; }
    }
    red[tid] = ls; __syncthreads();
    for (int s = 128; s; s >>= 1) {
        if (tid < s) red[tid] += red[tid + s];
        __syncthreads();
    }
    const float inv = 1.0f / red[0];
    if (act) {
        const size_t base = (size_t)blockIdx.x * S + tid * 8;
        float4 o0, o1;
        o0.x = e[0] * inv; o0.y = e[1] * inv; o0.z = e[2] * inv; o0.w = e[3] * inv;
        o1.x = e[4] * inv; o1.y = e[5] * inv; o1.z = e[6] * inv; o1.w = e[7] * inv;
        *(float4*)&out1[base] = o0; *(float4*)&out1[base + 4] = o1;
        if (out2) { *(float4*)&out2[base] = o0; *(float4*)&out2[base + 4] = o1; }
    }
}

// ---------------------------------------------------------------------------
// LayerNorm over rows of 512; fp32 out + optional bf16 out.
// ---------------------------------------------------------------------------
__global__ __launch_bounds__(256) void ln512(
    const float* __restrict__ X, const float* __restrict__ g,
    const float* __restrict__ be, float* __restrict__ Yf, u16* __restrict__ Yb)
{
    __shared__ float red[256];
    const int r = blockIdx.x, tid = threadIdx.x;
    const float* xr = X + (size_t)r * 512;
    const float x0 = xr[tid], x1 = xr[tid + 256];
    red[tid] = x0 + x1; __syncthreads();
    for (int st = 128; st; st >>= 1) {
        if (tid < st) red[tid] += red[tid + st];
        __syncthreads();
    }
    const float mean = red[0] * (1.0f / 512.0f); __syncthreads();
    const float d0 = x0 - mean, d1 = x1 - mean;
    red[tid] = d0 * d0 + d1 * d1; __syncthreads();
    for (int st = 128; st; st >>= 1) {
        if (tid < st) red[tid] += red[tid + st];
        __syncthreads();
    }
    const float rstd = rsqrtf(red[0] * (1.0f / 512.0f) + LN_EPS);
    const float y0 = d0 * rstd * g[tid] + be[tid];
    const float y1 = d1 * rstd * g[tid + 256] + be[tid + 256];
    float* yr = Yf + (size_t)r * 512;
    yr[tid] = y0; yr[tid + 256] = y1;
    if (Yb) {
        u16* yb = Yb + (size_t)r * 512;
        yb[tid] = f2bf(y0); yb[tid + 256] = f2bf(y1);
    }
}

// ---------------------------------------------------------------------------
// pair assembly: inverse map + gather rows to bf16.
// ---------------------------------------------------------------------------
__global__ void init_inv(int* __restrict__ inv) {
    const int i = blockIdx.x * 256 + threadIdx.x;
    if (i < 4096) inv[i] = -1;
}
__global__ void scatter_inv(int* __restrict__ inv, const int* __restrict__ ind, int n) {
    const int i = blockIdx.x * 256 + threadIdx.x;
    if (i < n) inv[ind[i]] = i;
}
__global__ void gather_rows_bf(
    u16* __restrict__ dst, const float* __restrict__ spf,
    const float* __restrict__ ep, const int* __restrict__ ind,
    const int* __restrict__ inv, int total4)
{
    const int e = blockIdx.x * 256 + threadIdx.x;
    if (e >= total4) return;
    const int row = e >> 7, c = e & 127;
    const int j = row >> 1, b = row & 1;
    const int idx = ind[j];
    const int iv = inv[idx];
    const float4* src = (iv >= 0) ? (const float4*)(spf + (size_t)(iv * 2 + b) * 512)
                                  : (const float4*)(ep + (size_t)(idx * 2 + b) * 512);
    const float4 v = src[c];
    ushort4 o; o.x = f2bf(v.x); o.y = f2bf(v.y); o.z = f2bf(v.z); o.w = f2bf(v.w);
    ((ushort4*)dst)[e] = o;
}

// ---------------------------------------------------------------------------
extern "C" void kernel_launch(void* const* d_in, const int* in_sizes, int n_in,
                              void* d_out, int out_size, void* d_ws, size_t ws_size,
                              hipStream_t stream)
{
    (void)in_sizes; (void)n_in; (void)out_size; (void)ws_size;

    const float* in_sp = (const float*)d_in[0];
    const float* in_su = (const float*)d_in[1];
    const float* in_ep = (const float*)d_in[2];
    const int* ind_pair = (const int*)d_in[3];
    const int* ind_e2e  = (const int*)d_in[4];
    const int* ind_n2e  = (const int*)d_in[5];
    const float *Wi_sa  = (const float*)d_in[6],  *bi_sa  = (const float*)d_in[7];
    const float *Wo_sa  = (const float*)d_in[8],  *bo_sa  = (const float*)d_in[9];
    const float *Wi_san = (const float*)d_in[10], *bi_san = (const float*)d_in[11];
    const float *Wo_san = (const float*)d_in[12], *bo_san = (const float*)d_in[13];
    const float *Wi_e2e = (const float*)d_in[14], *bi_e2e = (const float*)d_in[15];
    const float *Wo_e2e = (const float*)d_in[16], *bo_e2e = (const float*)d_in[17];
    const float *Wi_n2e = (const float*)d_in[18], *bi_n2e = (const float*)d_in[19];
    const float *Wo_n2e = (const float*)d_in[20], *bo_n2e = (const float*)d_in[21];
    const float *Wi_n2n = (const float*)d_in[22], *bi_n2n = (const float*)d_in[23];
    const float *Wo_n2n = (const float*)d_in[24], *bo_n2n = (const float*)d_in[25];
    const float *W1  = (const float*)d_in[26], *b1f  = (const float*)d_in[27];
    const float *W2  = (const float*)d_in[28], *b2f  = (const float*)d_in[29];
    const float *W1u = (const float*)d_in[30], *b1fu = (const float*)d_in[31];
    const float *W2u = (const float*)d_in[32], *b2fu = (const float*)d_in[33];
    const float *g1  = (const float*)d_in[34], *g1u = (const float*)d_in[35];
    const float *g2  = (const float*)d_in[36], *g3  = (const float*)d_in[37];
    const float *be1 = (const float*)d_in[38], *be1u = (const float*)d_in[39];
    const float *be2 = (const float*)d_in[40], *be3  = (const float*)d_in[41];

    float* Wf = (float*)d_ws;
    size_t of = 0;
    auto af_ = [&](size_t n) { float* p = Wf + of; of += n; return p; };
    float* spf    = af_((size_t)2048 * 512);
    float* suf    = af_((size_t)512 * 512);
    float* tmp0f  = af_((size_t)2048 * 512);
    float* tmp1f  = af_((size_t)2048 * 512);
    float* upn2ef = af_((size_t)512 * 512);
    float2* stats = (float2*)af_((size_t)2 * 16 * 1024);
    float2* pstat = (float2*)af_((size_t)2 * 16 * 1024 * 32);

    u16* Wu = (u16*)(Wf + of);
    size_t ou = 0;
    auto au_ = [&](size_t n) { u16* p = Wu + ou; ou += n; return p; };
    u16* in_spb = au_((size_t)2048 * 512);
    u16* in_sub = au_((size_t)512 * 512);
    u16* spb    = au_((size_t)2048 * 512);
    u16* sub    = au_((size_t)512 * 512);
    u16* ge2eb  = au_((size_t)4096 * 512);
    u16* gn2eb  = au_((size_t)4096 * 512);
    u16* qkvb   = au_((size_t)2048 * 1536);
    u16* kvb    = au_((size_t)4096 * 1024);
    u16* attb   = au_((size_t)2048 * 512);
    u16* tmp1b  = au_((size_t)2048 * 512);
    u16* ffnb   = au_((size_t)2048 * 2048);
    u16* vtb    = au_((size_t)16 * 64 * 2048);
    u16* probs  = au_((size_t)16 * 1024 * 2048);
    u16* wb[14];
    const int wsz[14] = {786432, 262144, 786432, 262144, 786432, 262144, 786432,
                         262144, 786432, 262144, 1048576, 1048576, 1048576, 1048576};
    for (int i = 0; i < 14; ++i) wb[i] = au_((size_t)wsz[i]);
    int* inv = (int*)(Wu + ou);

    float* out_uu = (float*)d_out;
    float* out_up = out_uu + 262144;
    float* out_w1 = out_up + 1048576;
    float* out_w2 = out_w1 + 4194304;
    float* out_w3 = out_w2 + 4194304;
    float* out_w4 = out_w3 + 1048576;

    const dim3 blk(256);

    CvtDesc cd;
    const float* wsrc[14] = {Wi_sa, Wo_sa, Wi_san, Wo_san, Wi_e2e, Wo_e2e, Wi_n2e,
                             Wo_n2e, Wi_n2n, Wo_n2n, W1, W2, W1u, W2u};
    for (int i = 0; i < 14; ++i) { cd.src[i] = wsrc[i]; cd.dst[i] = wb[i]; cd.n4[i] = wsz[i] / 4; }
    cd.src[14] = in_sp; cd.dst[14] = in_spb; cd.n4[14] = 1048576 / 4;
    cd.src[15] = in_su; cd.dst[15] = in_sub; cd.n4[15] = 262144 / 4;
    cvt_multi<<<dim3(1024, 16), blk, 0, stream>>>(cd);

    init_inv<<<16, blk, 0, stream>>>(inv);
    scatter_inv<<<4, blk, 0, stream>>>(inv, ind_pair, 1024);

    auto gemm = [&](int tile, const u16* A, int lda, int aOffB, int aOffH,
                    const u16* B, int ldb, int bOffB, int bOffH,
                    float* Cf, u16* Ch, int ldc, long cOffB, long cOffH,
                    const float* bias, const float* r1, const float* r2,
                    float scale, int relu, int M, int N, int K, int batch) {
        if (tile == 64)
            mfma_gemm<64, 64, false><<<dim3(N / 64, M / 64, batch), blk, 0, stream>>>(
                A, lda, aOffB, aOffH, B, ldb, bOffB, bOffH, Cf, Ch, ldc, cOffB, cOffH,
                bias, r1, r2, scale, relu, K, nullptr, 0, 0);
        else
            mfma_gemm<128, 128, false><<<dim3(N / 128, M / 128, batch), blk, 0, stream>>>(
                A, lda, aOffB, aOffH, B, ldb, bOffB, bOffH, Cf, Ch, ldc, cOffB, cOffH,
                bias, r1, r2, scale, relu, K, nullptr, 0, 0);
    };
    // Scores GEMM (batch 16) + per-row stat partials + merge.
    auto gemmScore = [&](int tile, const u16* A, int lda, int aOffB, int aOffH,
                         const u16* B, int ldb, int bOffB, int bOffH,
                         u16* Ch, int ldc, long cOffB, long cOffH,
                         int M, int N, int K) {
        const int nx = (N / tile) * 2;
        if (tile == 64)
            mfma_gemm<64, 64, true><<<dim3(N / 64, M / 64, 16), blk, 0, stream>>>(
                A, lda, aOffB, aOffH, B, ldb, bOffB, bOffH, nullptr, Ch, ldc, cOffB, cOffH,
                nullptr, nullptr, nullptr, 0.125f, 0, K, pstat, (long)M * nx, nx);
        else
            mfma_gemm<128, 128, true><<<dim3(N / 128, M / 128, 16), blk, 0, stream>>>(
                A, lda, aOffB, aOffH, B, ldb, bOffB, bOffH, nullptr, Ch, ldc, cOffB, cOffH,
                nullptr, nullptr, nullptr, 0.125f, 0, K, pstat, (long)M * nx, nx);
        merge_stats<<<(16 * M + 255) / 256, blk, 0, stream>>>(pstat, stats, 16 * M, nx);
    };
    // P @ V from RAW scores using precomputed stats (single probs pass).
    auto pv = [&](const u16* V, int ldv, int L, int S) {
        vtrans<<<dim3(S / 64, 16), blk, 0, stream>>>(V, ldv, vtb, S);
        pv2<<<dim3(L / 32, 16), blk, 0, stream>>>(probs, vtb, stats, attb, L, S);
    };

    // ================= self-attention (pair) =================
    gemm(128, in_spb, 512, 0, 0, wb[0], 512, 0, 0, nullptr, qkvb, 1536, 0, 0,
         bi_sa, nullptr, nullptr, 1.f, 0, 2048, 1536, 512, 1);
    gemmScore(128, qkvb, 3072, 1536, 64, qkvb + 512, 3072, 1536, 64, probs,
              1024, 1048576L, 2097152L, 1024, 1024, 64);
    pv(qkvb + 1024, 1536, 1024, 1024);
    gemm(64, attb, 512, 0, 0, wb[1], 512, 0, 0, tmp0f, nullptr, 512, 0, 0,
         bo_sa, in_sp, nullptr, 1.f, 0, 2048, 512, 512, 1);
    ln512<<<2048, blk, 0, stream>>>(tmp0f, g1, be1, spf, spb);

    // ================= self-attention (unary) =================
    gemm(64, in_sub, 512, 0, 0, wb[2], 512, 0, 0, nullptr, qkvb, 1536, 0, 0,
         bi_san, nullptr, nullptr, 1.f, 0, 512, 1536, 512, 1);
    gemmScore(64, qkvb, 3072, 1536, 64, qkvb + 512, 3072, 1536, 64, probs,
              256, 65536L, 131072L, 256, 256, 64);
    pv(qkvb + 1024, 1536, 256, 256);
    gemm(64, attb, 512, 0, 0, wb[3], 512, 0, 0, tmp0f, nullptr, 512, 0, 0,
         bo_san, in_su, nullptr, 1.f, 0, 512, 512, 512, 1);
    ln512<<<512, blk, 0, stream>>>(tmp0f, g1u, be1u, suf, sub);

    // ================= gathers =================
    gather_rows_bf<<<2048, blk, 0, stream>>>(ge2eb, spf, in_ep, ind_e2e, inv, 524288);
    gather_rows_bf<<<2048, blk, 0, stream>>>(gn2eb, spf, in_ep, ind_n2e, inv, 524288);

    // ================= e2e cross-attention =================
    gemm(64, spb, 512, 0, 0, wb[4], 512, 0, 0, nullptr, qkvb, 512, 0, 0,
         bi_e2e, nullptr, nullptr, 1.f, 0, 2048, 512, 512, 1);
    gemm(128, ge2eb, 512, 0, 0, wb[4] + 262144, 512, 0, 0, nullptr, kvb, 1024, 0, 0,
         bi_e2e + 512, nullptr, nullptr, 1.f, 0, 4096, 1024, 512, 1);
    gemmScore(128, qkvb, 1024, 512, 64, kvb, 2048, 1024, 64, probs,
              2048, 2097152L, 4194304L, 1024, 2048, 64);
    pv(kvb + 512, 1024, 1024, 2048);
    avg_softmax_f<<<2048, blk, 0, stream>>>(probs, stats, 1024, 2048, out_w1, out_w2);
    gemm(64, attb, 512, 0, 0, wb[5], 512, 0, 0, tmp0f, nullptr, 512, 0, 0,
         bo_e2e, spf, nullptr, 2.f, 0, 2048, 512, 512, 1);
    ln512<<<2048, blk, 0, stream>>>(tmp0f, g2, be2, tmp1f, tmp1b);
    // FFN (pair)
    gemm(128, tmp1b, 512, 0, 0, wb[10], 512, 0, 0, nullptr, ffnb, 2048, 0, 0,
         b1f, nullptr, nullptr, 1.f, 1, 2048, 2048, 512, 1);
    gemm(64, ffnb, 2048, 0, 0, wb[11], 2048, 0, 0, tmp0f, nullptr, 512, 0, 0,
         b2f, tmp1f, nullptr, 1.f, 0, 2048, 512, 2048, 1);
    ln512<<<2048, blk, 0, stream>>>(tmp0f, g3, be3, out_up, nullptr);

    // ================= n2e cross-attention =================
    gemm(64, sub, 512, 0, 0, wb[6], 512, 0, 0, nullptr, qkvb, 512, 0, 0,
         bi_n2e, nullptr, nullptr, 1.f, 0, 512, 512, 512, 1);
    gemm(128, gn2eb, 512, 0, 0, wb[6] + 262144, 512, 0, 0, nullptr, kvb, 1024, 0, 0,
         bi_n2e + 512, nullptr, nullptr, 1.f, 0, 4096, 1024, 512, 1);
    gemmScore(128, qkvb, 1024, 512, 64, kvb, 2048, 1024, 64, probs,
              2048, 524288L, 1048576L, 256, 2048, 64);
    pv(kvb + 512, 1024, 256, 2048);
    avg_softmax_f<<<512, blk, 0, stream>>>(probs, stats, 256, 2048, out_w3, nullptr);
    gemm(64, attb, 512, 0, 0, wb[7], 512, 0, 0, upn2ef, nullptr, 512, 0, 0,
         bo_n2e, nullptr, nullptr, 1.f, 0, 512, 512, 512, 1);

    // ================= n2n self-attention =================
    gemm(64, sub, 512, 0, 0, wb[8], 512, 0, 0, nullptr, qkvb, 1536, 0, 0,
         bi_n2n, nullptr, nullptr, 1.f, 0, 512, 1536, 512, 1);
    gemmScore(64, qkvb, 3072, 1536, 64, qkvb + 512, 3072, 1536, 64, probs,
              256, 65536L, 131072L, 256, 256, 64);
    pv(qkvb + 1024, 1536, 256, 256);
    avg_softmax_f<<<512, blk, 0, stream>>>(probs, stats, 256, 256, out_w4, nullptr);
    gemm(64, attb, 512, 0, 0, wb[9], 512, 0, 0, tmp0f, nullptr, 512, 0, 0,
         bo_n2n, suf, upn2ef, 1.f, 0, 512, 512, 512, 1);
    ln512<<<512, blk, 0, stream>>>(tmp0f, g2, be2, tmp1f, tmp1b);
    // FFN (unary)
    gemm(64, tmp1b, 512, 0, 0, wb[12], 512, 0, 0, nullptr, ffnb, 2048, 0, 0,
         b1fu, nullptr, nullptr, 1.f, 1, 512, 2048, 512, 1);
    gemm(64, ffnb, 2048, 0, 0, wb[13], 2048, 0, 0, tmp0f, nullptr, 512, 0, 0,
         b2fu, tmp1f, nullptr, 1.f, 0, 512, 512, 2048, 1);
    ln512<<<512, blk, 0, stream>>>(tmp0f, g3, be3, out_uu, nullptr);
}

// Round 9
// 684.664 us; speedup vs baseline: 1.0736x; 1.0736x over previous
//
#include <hip/hip_runtime.h>
#include <cstddef>

#define LN_EPS 1e-5f

typedef unsigned short u16;
typedef short short8 __attribute__((ext_vector_type(8)));
typedef float f32x4 __attribute__((ext_vector_type(4)));

__device__ __forceinline__ u16 f2bf(float f) {
    unsigned int u = __float_as_uint(f);
    u = (u + 0x7FFFu + ((u >> 16) & 1u)) >> 16;
    return (u16)u;
}
__device__ __forceinline__ float bf2f(u16 h) {
    return __uint_as_float((unsigned int)h << 16);
}

// ---------------------------------------------------------------------------
// Multi-tensor fp32 -> bf16 convert (weights + inputs), one launch.
// ---------------------------------------------------------------------------
struct CvtDesc {
    const float* src[16];
    u16* dst[16];
    int n4[16];
};
__global__ __launch_bounds__(256) void cvt_multi(CvtDesc d) {
    const int t = blockIdx.x * 256 + threadIdx.x;
    const int i = blockIdx.y;
    if (t >= d.n4[i]) return;
    const float4 v = ((const float4*)d.src[i])[t];
    ushort4 o;
    o.x = f2bf(v.x); o.y = f2bf(v.y); o.z = f2bf(v.z); o.w = f2bf(v.w);
    ((ushort4*)d.dst[i])[t] = o;
}

// ---------------------------------------------------------------------------
// bf16 MFMA NT GEMM, BMxBN tile, 4 waves (2x2), BK=32, 16x16x32 MFMA.
// LDS rows padded to 40 u16; K-loop register-prefetches the next chunk.
// C = scale*(A@B^T + bias) + res1 + res2 (+relu). Outputs fp32 and/or bf16.
// (R8's STATS epilogue reverted: shuffle-reductions in the epilogue cost
//  ~30 us/dispatch — measured regression.)
// ---------------------------------------------------------------------------
template<int BM, int BN>
__global__ __launch_bounds__(256) void mfma_gemm(
    const u16* __restrict__ A, int lda,
    const u16* __restrict__ B, int ldb,
    float* __restrict__ Cf, u16* __restrict__ Ch, int ldc,
    const float* __restrict__ bias,
    const float* __restrict__ res1, const float* __restrict__ res2,
    float scale, int relu, int K)
{
    constexpr int MF = BM / 32;
    constexpr int NF = BN / 32;
    constexpr int MC = BM / 64;
    constexpr int NC = BN / 64;
    __shared__ u16 As[BM * 40];
    __shared__ u16 Bs[BN * 40];

    const int tid = threadIdx.x;
    const int wave = tid >> 6, lane = tid & 63;
    const int wm = wave >> 1, wn = wave & 1;
    const int m0 = blockIdx.y * BM, n0 = blockIdx.x * BN;

    f32x4 acc[MF][NF];
#pragma unroll
    for (int mf = 0; mf < MF; ++mf)
#pragma unroll
        for (int nf = 0; nf < NF; ++nf) acc[mf][nf] = (f32x4){0.f, 0.f, 0.f, 0.f};

    const int ar = tid >> 2, ac = (tid & 3) * 8;
    const int ml = lane & 15, kq = lane >> 4;

    short8 aN[MC], bN[NC];
#pragma unroll
    for (int c = 0; c < MC; ++c)
        aN[c] = *(const short8*)&A[(size_t)(m0 + ar + c * 64) * lda + ac];
#pragma unroll
    for (int c = 0; c < NC; ++c)
        bN[c] = *(const short8*)&B[(size_t)(n0 + ar + c * 64) * ldb + ac];

    for (int k0 = 0; k0 < K; k0 += 32) {
        short8 aS[MC], bS[NC];
#pragma unroll
        for (int c = 0; c < MC; ++c) aS[c] = aN[c];
#pragma unroll
        for (int c = 0; c < NC; ++c) bS[c] = bN[c];
        if (k0 + 32 < K) {
#pragma unroll
            for (int c = 0; c < MC; ++c)
                aN[c] = *(const short8*)&A[(size_t)(m0 + ar + c * 64) * lda + k0 + 32 + ac];
#pragma unroll
            for (int c = 0; c < NC; ++c)
                bN[c] = *(const short8*)&B[(size_t)(n0 + ar + c * 64) * ldb + k0 + 32 + ac];
        }
        __syncthreads();
#pragma unroll
        for (int c = 0; c < MC; ++c) *(short8*)&As[(ar + c * 64) * 40 + ac] = aS[c];
#pragma unroll
        for (int c = 0; c < NC; ++c) *(short8*)&Bs[(ar + c * 64) * 40 + ac] = bS[c];
        __syncthreads();

        short8 af[MF], bfr[NF];
#pragma unroll
        for (int mf = 0; mf < MF; ++mf)
            af[mf] = *(const short8*)&As[(wm * (BM / 2) + mf * 16 + ml) * 40 + kq * 8];
#pragma unroll
        for (int nf = 0; nf < NF; ++nf)
            bfr[nf] = *(const short8*)&Bs[(wn * (BN / 2) + nf * 16 + ml) * 40 + kq * 8];
#pragma unroll
        for (int mf = 0; mf < MF; ++mf)
#pragma unroll
            for (int nf = 0; nf < NF; ++nf)
                acc[mf][nf] = __builtin_amdgcn_mfma_f32_16x16x32_bf16(
                    af[mf], bfr[nf], acc[mf][nf], 0, 0, 0);
    }

    const int rq = lane >> 4;
#pragma unroll
    for (int mf = 0; mf < MF; ++mf)
#pragma unroll
        for (int nf = 0; nf < NF; ++nf) {
            const int col = n0 + wn * (BN / 2) + nf * 16 + ml;
            const float bv = bias ? bias[col] : 0.f;
#pragma unroll
            for (int r = 0; r < 4; ++r) {
                const int row = m0 + wm * (BM / 2) + mf * 16 + rq * 4 + r;
                float v = scale * (acc[mf][nf][r] + bv);
                const size_t idx = (size_t)row * ldc + col;
                if (res1) v += res1[idx];
                if (res2) v += res2[idx];
                if (relu) v = fmaxf(v, 0.f);
                if (Cf) Cf[idx] = v;
                if (Ch) Ch[idx] = f2bf(v);
            }
        }
}

// ---------------------------------------------------------------------------
// Fused attention core. Block = (bh, ROWS q-rows). 4 waves.
//  A: scores = 0.125 * Q K^T via MFMA; raw bf16 scores -> global (needed by
//     avg_softmax_f); rows stay L2-resident for phases B/C.
//  B: per-row (max, 1/sumexp) by streaming the block's own rows (cheap,
//     no shuffles); stats -> LDS + global.
//  C: PV MFMA over S with exp(s-m)*inv applied at LDS staging (pv2 pattern).
// ROWS=32: waves 2x2 (16 rows x 32 cols); ROWS=16: waves 1x4 (16 x 16).
// ---------------------------------------------------------------------------
template<int ROWS>
__global__ __launch_bounds__(256) void attn_fused(
    const u16* __restrict__ Q, int ldq,
    const u16* __restrict__ Kp, int ldk,
    const u16* __restrict__ vT,
    u16* __restrict__ scores, float2* __restrict__ stats,
    u16* __restrict__ att, int L, int S)
{
    constexpr int WN   = (ROWS == 32) ? 2 : 4;
    constexpr int SPAN = 64 / WN;          // s-cols per wave per 64-chunk
    constexpr int NF   = SPAN / 16;
    constexpr int AF   = ROWS / 16;
    constexpr int TPR  = 256 / ROWS;       // threads per row in phase B

    __shared__ u16 Qs[ROWS * 72];
    __shared__ u16 Ks[64 * 72];
    __shared__ u16 Ax[ROWS * 40];
    __shared__ u16 Bx[64 * 40];
    __shared__ float rm[ROWS][TPR + 1];
    __shared__ float rs[ROWS][TPR + 1];
    __shared__ float smax[ROWS], sinv[ROWS];

    const int tid = threadIdx.x;
    const int wave = tid >> 6, lane = tid & 63;
    const int ml = lane & 15, rq = lane >> 4;
    const int wm = wave / WN, wn = wave % WN;
    const int i0 = blockIdx.x * ROWS;
    const int bz = blockIdx.y, bb = bz & 1, hh = bz >> 1;
    u16* Sb = scores + (size_t)bz * L * S + (size_t)i0 * S;
    const u16* Vb = vT + (size_t)bz * 64 * S;

    // ---- stage Q tile (ROWS x 64)
    if (tid < ROWS * 8) {
        const int r = tid >> 3, dc = (tid & 7) * 8;
        *(short8*)&Qs[r * 72 + dc] =
            *(const short8*)&Q[(size_t)((i0 + r) * 2 + bb) * ldq + hh * 64 + dc];
    }
    __syncthreads();
    const short8 qf0 = *(const short8*)&Qs[(wm * 16 + ml) * 72 + rq * 8];
    const short8 qf1 = *(const short8*)&Qs[(wm * 16 + ml) * 72 + 32 + rq * 8];

    // ---- phase A: scores
    for (int k0 = 0; k0 < S; k0 += 64) {
        __syncthreads();
#pragma unroll
        for (int c = 0; c < 2; ++c) {
            const int idx = tid + c * 256;
            const int sr = idx >> 3, dc = (idx & 7) * 8;
            *(short8*)&Ks[sr * 72 + dc] =
                *(const short8*)&Kp[(size_t)((k0 + sr) * 2 + bb) * ldk + hh * 64 + dc];
        }
        __syncthreads();
#pragma unroll
        for (int nf = 0; nf < NF; ++nf) {
            const int sb = wn * SPAN + nf * 16;
            const short8 kf0 = *(const short8*)&Ks[(sb + ml) * 72 + rq * 8];
            const short8 kf1 = *(const short8*)&Ks[(sb + ml) * 72 + 32 + rq * 8];
            f32x4 sc = (f32x4){0.f, 0.f, 0.f, 0.f};
            sc = __builtin_amdgcn_mfma_f32_16x16x32_bf16(qf0, kf0, sc, 0, 0, 0);
            sc = __builtin_amdgcn_mfma_f32_16x16x32_bf16(qf1, kf1, sc, 0, 0, 0);
#pragma unroll
            for (int r = 0; r < 4; ++r) {
                const int row = wm * 16 + rq * 4 + r;
                Sb[(size_t)row * S + k0 + sb + ml] = f2bf(sc[r] * 0.125f);
            }
        }
    }
    __syncthreads();   // drain score stores -> visible to whole block via L2

    // ---- phase B: per-row stats from the (rounded) stored scores
    {
        const int r1 = tid / TPR, q1 = tid % TPR;
        const int chunk = S / TPR;
        const u16* rp = Sb + (size_t)r1 * S + q1 * chunk;
        float m = -1e30f, s = 0.f;
        for (int c = 0; c < chunk; c += 8) {
            const short8 v8 = *(const short8*)&rp[c];
            float v[8], m8 = -1e30f;
#pragma unroll
            for (int j = 0; j < 8; ++j) { v[j] = bf2f((u16)v8[j]); m8 = fmaxf(m8, v[j]); }
            float s8 = 0.f;
#pragma unroll
            for (int j = 0; j < 8; ++j) s8 += __expf(v[j] - m8);
            const float nm = fmaxf(m, m8);
            s = s * __expf(m - nm) + s8 * __expf(m8 - nm);
            m = nm;
        }
        rm[r1][q1] = m; rs[r1][q1] = s;
    }
    __syncthreads();
    if ((tid % TPR) == 0) {
        const int r1 = tid / TPR;
        float mm = rm[r1][0], ss = rs[r1][0];
#pragma unroll
        for (int j = 1; j < TPR; ++j) {
            const float nm = fmaxf(mm, rm[r1][j]);
            ss = ss * __expf(mm - nm) + rs[r1][j] * __expf(rm[r1][j] - nm);
            mm = nm;
        }
        const float iv = 1.0f / ss;
        smax[r1] = mm; sinv[r1] = iv;
        stats[(size_t)bz * L + i0 + r1] = make_float2(mm, iv);
    }
    __syncthreads();

    // ---- phase C: PV (exp fused at staging; register prefetch; BK=32)
    const int rA = tid >> 2, acC = (tid & 3) * 8;
    const int rB = tid >> 2;                      // 0..63 for V^T rows (d)
    const bool doA = tid < ROWS * 4;
    float mxv = 0.f, invv = 1.f;
    if (doA) { mxv = smax[rA]; invv = sinv[rA]; }

    f32x4 acc[AF];
#pragma unroll
    for (int mf = 0; mf < AF; ++mf) acc[mf] = (f32x4){0.f, 0.f, 0.f, 0.f};

    short8 aN = {};
    if (doA) aN = *(const short8*)&Sb[(size_t)rA * S + acC];
    short8 bN = *(const short8*)&Vb[(size_t)rB * S + acC];

    for (int k0 = 0; k0 < S; k0 += 32) {
        short8 aS = {};
        if (doA) {
#pragma unroll
            for (int j = 0; j < 8; ++j)
                aS[j] = (short)f2bf(__expf(bf2f((u16)aN[j]) - mxv) * invv);
        }
        const short8 bS = bN;
        if (k0 + 32 < S) {
            if (doA) aN = *(const short8*)&Sb[(size_t)rA * S + k0 + 32 + acC];
            bN = *(const short8*)&Vb[(size_t)rB * S + k0 + 32 + acC];
        }
        __syncthreads();
        if (doA) *(short8*)&Ax[rA * 40 + acC] = aS;
        *(short8*)&Bx[rB * 40 + acC] = bS;
        __syncthreads();

        short8 afr[AF];
#pragma unroll
        for (int mf = 0; mf < AF; ++mf)
            afr[mf] = *(const short8*)&Ax[(mf * 16 + ml) * 40 + rq * 8];
        const short8 bfr = *(const short8*)&Bx[(wave * 16 + ml) * 40 + rq * 8];
#pragma unroll
        for (int mf = 0; mf < AF; ++mf)
            acc[mf] = __builtin_amdgcn_mfma_f32_16x16x32_bf16(afr[mf], bfr, acc[mf], 0, 0, 0);
    }

#pragma unroll
    for (int mf = 0; mf < AF; ++mf)
#pragma unroll
        for (int rr = 0; rr < 4; ++rr) {
            const int i = i0 + mf * 16 + rq * 4 + rr;
            const int d = wave * 16 + ml;
            att[((size_t)i * 2 + bb) * 512 + hh * 64 + d] = f2bf(acc[mf][rr]);
        }
}

// ---------------------------------------------------------------------------
// One-time V transpose: vT[bh][d][s] = V[(s*2+b)*ldv + h*64 + d]  (bf16).
// ---------------------------------------------------------------------------
__global__ __launch_bounds__(256) void vtrans(
    const u16* __restrict__ V, int ldv, u16* __restrict__ vT, int S)
{
    __shared__ u16 Vs[64 * 72];
    const int tid = threadIdx.x;
    const int s0 = blockIdx.x * 64;
    const int bh = blockIdx.y, b = bh & 1, h = bh >> 1;

#pragma unroll
    for (int c = 0; c < 2; ++c) {
        const int idx = tid + c * 256;
        const int sr = idx >> 3, dc = (idx & 7) * 8;
        *(short8*)&Vs[sr * 72 + dc] =
            *(const short8*)&V[(size_t)((s0 + sr) * 2 + b) * ldv + h * 64 + dc];
    }
    __syncthreads();
#pragma unroll
    for (int c = 0; c < 2; ++c) {
        const int idx = tid + c * 256;
        const int dr = idx >> 3, sc = (idx & 7) * 8;
        short8 o;
#pragma unroll
        for (int j = 0; j < 8; ++j) o[j] = (short)Vs[(sc + j) * 72 + dr];
        *(short8*)&vT[(size_t)bh * 64 * S + (size_t)dr * S + s0 + sc] = o;
    }
}

// ---------------------------------------------------------------------------
// Head-average of (stats-normalized) probs from RAW scores + second softmax
// -> fp32 out (1 or 2 copies). grid = 2*L, blockIdx.x = b*L + i.
// ---------------------------------------------------------------------------
__global__ __launch_bounds__(256) void avg_softmax_f(
    const u16* __restrict__ P, const float2* __restrict__ st, int L, int S,
    float* __restrict__ out1, float* __restrict__ out2)
{
    __shared__ float red[256];
    const int tid = threadIdx.x;
    const bool act = tid * 8 < S;
    const int b = blockIdx.x / L, i = blockIdx.x % L;
    const size_t LS = (size_t)L * S;

    float acc[8] = {};
    if (act) {
#pragma unroll
        for (int h = 0; h < 8; ++h) {
            const int bh = h * 2 + b;
            const float2 s = st[(size_t)bh * L + i];
            const short8 r8 = *(const short8*)&P[(size_t)bh * LS + (size_t)i * S + tid * 8];
#pragma unroll
            for (int j = 0; j < 8; ++j)
                acc[j] += __expf(bf2f((u16)r8[j]) - s.x) * s.y;
        }
#pragma unroll
        for (int j = 0; j < 8; ++j) acc[j] *= 0.125f;
    }
    float lmax = -1e30f;
    if (act) {
#pragma unroll
        for (int j = 0; j < 8; ++j) lmax = fmaxf(lmax, acc[j]);
    }
    red[tid] = lmax; __syncthreads();
    for (int s = 128; s; s >>= 1) {
        if (tid < s) red[tid] = fmaxf(red[tid], red[tid + s]);
        __syncthreads();
    }
    const float mx = red[0]; __syncthreads();
    float e[8];
    float ls = 0.f;
    if (act) {
#pragma unroll
        for (int j = 0; j < 8; ++j) { e[j] = __expf(acc[j] - mx); ls += e[j]; }
    }
    red[tid] = ls; __syncthreads();
    for (int s = 128; s; s >>= 1) {
        if (tid < s) red[tid] += red[tid + s];
        __syncthreads();
    }
    const float inv = 1.0f / red[0];
    if (act) {
        const size_t base = (size_t)blockIdx.x * S + tid * 8;
        float4 o0, o1;
        o0.x = e[0] * inv; o0.y = e[1] * inv; o0.z = e[2] * inv; o0.w = e[3] * inv;
        o1.x = e[4] * inv; o1.y = e[5] * inv; o1.z = e[6] * inv; o1.w = e[7] * inv;
        *(float4*)&out1[base] = o0; *(float4*)&out1[base + 4] = o1;
        if (out2) { *(float4*)&out2[base] = o0; *(float4*)&out2[base + 4] = o1; }
    }
}

// ---------------------------------------------------------------------------
// LayerNorm over rows of 512; fp32 out + optional bf16 out.
// ---------------------------------------------------------------------------
__global__ __launch_bounds__(256) void ln512(
    const float* __restrict__ X, const float* __restrict__ g,
    const float* __restrict__ be, float* __restrict__ Yf, u16* __restrict__ Yb)
{
    __shared__ float red[256];
    const int r = blockIdx.x, tid = threadIdx.x;
    const float* xr = X + (size_t)r * 512;
    const float x0 = xr[tid], x1 = xr[tid + 256];
    red[tid] = x0 + x1; __syncthreads();
    for (int st = 128; st; st >>= 1) {
        if (tid < st) red[tid] += red[tid + st];
        __syncthreads();
    }
    const float mean = red[0] * (1.0f / 512.0f); __syncthreads();
    const float d0 = x0 - mean, d1 = x1 - mean;
    red[tid] = d0 * d0 + d1 * d1; __syncthreads();
    for (int st = 128; st; st >>= 1) {
        if (tid < st) red[tid] += red[tid + st];
        __syncthreads();
    }
    const float rstd = rsqrtf(red[0] * (1.0f / 512.0f) + LN_EPS);
    const float y0 = d0 * rstd * g[tid] + be[tid];
    const float y1 = d1 * rstd * g[tid + 256] + be[tid + 256];
    float* yr = Yf + (size_t)r * 512;
    yr[tid] = y0; yr[tid + 256] = y1;
    if (Yb) {
        u16* yb = Yb + (size_t)r * 512;
        yb[tid] = f2bf(y0); yb[tid + 256] = f2bf(y1);
    }
}

// ---------------------------------------------------------------------------
// pair assembly: inverse map + gather rows to bf16.
// ---------------------------------------------------------------------------
__global__ void init_inv(int* __restrict__ inv) {
    const int i = blockIdx.x * 256 + threadIdx.x;
    if (i < 4096) inv[i] = -1;
}
__global__ void scatter_inv(int* __restrict__ inv, const int* __restrict__ ind, int n) {
    const int i = blockIdx.x * 256 + threadIdx.x;
    if (i < n) inv[ind[i]] = i;
}
__global__ void gather_rows_bf(
    u16* __restrict__ dst, const float* __restrict__ spf,
    const float* __restrict__ ep, const int* __restrict__ ind,
    const int* __restrict__ inv, int total4)
{
    const int e = blockIdx.x * 256 + threadIdx.x;
    if (e >= total4) return;
    const int row = e >> 7, c = e & 127;
    const int j = row >> 1, b = row & 1;
    const int idx = ind[j];
    const int iv = inv[idx];
    const float4* src = (iv >= 0) ? (const float4*)(spf + (size_t)(iv * 2 + b) * 512)
                                  : (const float4*)(ep + (size_t)(idx * 2 + b) * 512);
    const float4 v = src[c];
    ushort4 o; o.x = f2bf(v.x); o.y = f2bf(v.y); o.z = f2bf(v.z); o.w = f2bf(v.w);
    ((ushort4*)dst)[e] = o;
}

// ---------------------------------------------------------------------------
extern "C" void kernel_launch(void* const* d_in, const int* in_sizes, int n_in,
                              void* d_out, int out_size, void* d_ws, size_t ws_size,
                              hipStream_t stream)
{
    (void)in_sizes; (void)n_in; (void)out_size; (void)ws_size;

    const float* in_sp = (const float*)d_in[0];
    const float* in_su = (const float*)d_in[1];
    const float* in_ep = (const float*)d_in[2];
    const int* ind_pair = (const int*)d_in[3];
    const int* ind_e2e  = (const int*)d_in[4];
    const int* ind_n2e  = (const int*)d_in[5];
    const float *Wi_sa  = (const float*)d_in[6],  *bi_sa  = (const float*)d_in[7];
    const float *Wo_sa  = (const float*)d_in[8],  *bo_sa  = (const float*)d_in[9];
    const float *Wi_san = (const float*)d_in[10], *bi_san = (const float*)d_in[11];
    const float *Wo_san = (const float*)d_in[12], *bo_san = (const float*)d_in[13];
    const float *Wi_e2e = (const float*)d_in[14], *bi_e2e = (const float*)d_in[15];
    const float *Wo_e2e = (const float*)d_in[16], *bo_e2e = (const float*)d_in[17];
    const float *Wi_n2e = (const float*)d_in[18], *bi_n2e = (const float*)d_in[19];
    const float *Wo_n2e = (const float*)d_in[20], *bo_n2e = (const float*)d_in[21];
    const float *Wi_n2n = (const float*)d_in[22], *bi_n2n = (const float*)d_in[23];
    const float *Wo_n2n = (const float*)d_in[24], *bo_n2n = (const float*)d_in[25];
    const float *W1  = (const float*)d_in[26], *b1f  = (const float*)d_in[27];
    const float *W2  = (const float*)d_in[28], *b2f  = (const float*)d_in[29];
    const float *W1u = (const float*)d_in[30], *b1fu = (const float*)d_in[31];
    const float *W2u = (const float*)d_in[32], *b2fu = (const float*)d_in[33];
    const float *g1  = (const float*)d_in[34], *g1u = (const float*)d_in[35];
    const float *g2  = (const float*)d_in[36], *g3  = (const float*)d_in[37];
    const float *be1 = (const float*)d_in[38], *be1u = (const float*)d_in[39];
    const float *be2 = (const float*)d_in[40], *be3  = (const float*)d_in[41];

    float* Wf = (float*)d_ws;
    size_t of = 0;
    auto af_ = [&](size_t n) { float* p = Wf + of; of += n; return p; };
    float* spf    = af_((size_t)2048 * 512);
    float* suf    = af_((size_t)512 * 512);
    float* tmp0f  = af_((size_t)2048 * 512);
    float* tmp1f  = af_((size_t)2048 * 512);
    float* upn2ef = af_((size_t)512 * 512);
    float2* stats = (float2*)af_((size_t)2 * 16 * 1024);

    u16* Wu = (u16*)(Wf + of);
    size_t ou = 0;
    auto au_ = [&](size_t n) { u16* p = Wu + ou; ou += n; return p; };
    u16* in_spb = au_((size_t)2048 * 512);
    u16* in_sub = au_((size_t)512 * 512);
    u16* spb    = au_((size_t)2048 * 512);
    u16* sub    = au_((size_t)512 * 512);
    u16* ge2eb  = au_((size_t)4096 * 512);
    u16* gn2eb  = au_((size_t)4096 * 512);
    u16* qkvb   = au_((size_t)2048 * 1536);
    u16* kvb    = au_((size_t)4096 * 1024);
    u16* attb   = au_((size_t)2048 * 512);
    u16* tmp1b  = au_((size_t)2048 * 512);
    u16* ffnb   = au_((size_t)2048 * 2048);
    u16* vtb    = au_((size_t)16 * 64 * 2048);
    u16* probs  = au_((size_t)16 * 1024 * 2048);
    u16* wb[14];
    const int wsz[14] = {786432, 262144, 786432, 262144, 786432, 262144, 786432,
                         262144, 786432, 262144, 1048576, 1048576, 1048576, 1048576};
    for (int i = 0; i < 14; ++i) wb[i] = au_((size_t)wsz[i]);
    int* inv = (int*)(Wu + ou);

    float* out_uu = (float*)d_out;
    float* out_up = out_uu + 262144;
    float* out_w1 = out_up + 1048576;
    float* out_w2 = out_w1 + 4194304;
    float* out_w3 = out_w2 + 4194304;
    float* out_w4 = out_w3 + 1048576;

    const dim3 blk(256);

    CvtDesc cd;
    const float* wsrc[14] = {Wi_sa, Wo_sa, Wi_san, Wo_san, Wi_e2e, Wo_e2e, Wi_n2e,
                             Wo_n2e, Wi_n2n, Wo_n2n, W1, W2, W1u, W2u};
    for (int i = 0; i < 14; ++i) { cd.src[i] = wsrc[i]; cd.dst[i] = wb[i]; cd.n4[i] = wsz[i] / 4; }
    cd.src[14] = in_sp; cd.dst[14] = in_spb; cd.n4[14] = 1048576 / 4;
    cd.src[15] = in_su; cd.dst[15] = in_sub; cd.n4[15] = 262144 / 4;
    cvt_multi<<<dim3(1024, 16), blk, 0, stream>>>(cd);

    init_inv<<<16, blk, 0, stream>>>(inv);
    scatter_inv<<<4, blk, 0, stream>>>(inv, ind_pair, 1024);

    auto gemm = [&](int tile, const u16* A, int lda, const u16* B, int ldb,
                    float* Cf, u16* Ch, int ldc,
                    const float* bias, const float* r1, const float* r2,
                    float scale, int relu, int M, int N, int K) {
        if (tile == 64)
            mfma_gemm<64, 64><<<dim3(N / 64, M / 64), blk, 0, stream>>>(
                A, lda, B, ldb, Cf, Ch, ldc, bias, r1, r2, scale, relu, K);
        else
            mfma_gemm<128, 128><<<dim3(N / 128, M / 128), blk, 0, stream>>>(
                A, lda, B, ldb, Cf, Ch, ldc, bias, r1, r2, scale, relu, K);
    };
    // full attention core: vtrans + fused scores/stats/PV
    auto attn = [&](const u16* Q, int ldq, const u16* Kp, int ldk,
                    const u16* V, int ldv, int L, int S) {
        vtrans<<<dim3(S / 64, 16), blk, 0, stream>>>(V, ldv, vtb, S);
        if (L >= 1024)
            attn_fused<32><<<dim3(L / 32, 16), blk, 0, stream>>>(
                Q, ldq, Kp, ldk, vtb, probs, stats, attb, L, S);
        else
            attn_fused<16><<<dim3(L / 16, 16), blk, 0, stream>>>(
                Q, ldq, Kp, ldk, vtb, probs, stats, attb, L, S);
    };

    // ================= self-attention (pair) =================
    gemm(128, in_spb, 512, wb[0], 512, nullptr, qkvb, 1536,
         bi_sa, nullptr, nullptr, 1.f, 0, 2048, 1536, 512);
    attn(qkvb, 1536, qkvb + 512, 1536, qkvb + 1024, 1536, 1024, 1024);
    gemm(64, attb, 512, wb[1], 512, tmp0f, nullptr, 512,
         bo_sa, in_sp, nullptr, 1.f, 0, 2048, 512, 512);
    ln512<<<2048, blk, 0, stream>>>(tmp0f, g1, be1, spf, spb);

    // ================= self-attention (unary) =================
    gemm(64, in_sub, 512, wb[2], 512, nullptr, qkvb, 1536,
         bi_san, nullptr, nullptr, 1.f, 0, 512, 1536, 512);
    attn(qkvb, 1536, qkvb + 512, 1536, qkvb + 1024, 1536, 256, 256);
    gemm(64, attb, 512, wb[3], 512, tmp0f, nullptr, 512,
         bo_san, in_su, nullptr, 1.f, 0, 512, 512, 512);
    ln512<<<512, blk, 0, stream>>>(tmp0f, g1u, be1u, suf, sub);

    // ================= gathers =================
    gather_rows_bf<<<2048, blk, 0, stream>>>(ge2eb, spf, in_ep, ind_e2e, inv, 524288);
    gather_rows_bf<<<2048, blk, 0, stream>>>(gn2eb, spf, in_ep, ind_n2e, inv, 524288);

    // ================= e2e cross-attention =================
    gemm(64, spb, 512, wb[4], 512, nullptr, qkvb, 512,
         bi_e2e, nullptr, nullptr, 1.f, 0, 2048, 512, 512);
    gemm(128, ge2eb, 512, wb[4] + 262144, 512, nullptr, kvb, 1024,
         bi_e2e + 512, nullptr, nullptr, 1.f, 0, 4096, 1024, 512);
    attn(qkvb, 512, kvb, 1024, kvb + 512, 1024, 1024, 2048);
    avg_softmax_f<<<2048, blk, 0, stream>>>(probs, stats, 1024, 2048, out_w1, out_w2);
    gemm(64, attb, 512, wb[5], 512, tmp0f, nullptr, 512,
         bo_e2e, spf, nullptr, 2.f, 0, 2048, 512, 512);
    ln512<<<2048, blk, 0, stream>>>(tmp0f, g2, be2, tmp1f, tmp1b);
    // FFN (pair)
    gemm(128, tmp1b, 512, wb[10], 512, nullptr, ffnb, 2048,
         b1f, nullptr, nullptr, 1.f, 1, 2048, 2048, 512);
    gemm(64, ffnb, 2048, wb[11], 2048, tmp0f, nullptr, 512,
         b2f, tmp1f, nullptr, 1.f, 0, 2048, 512, 2048);
    ln512<<<2048, blk, 0, stream>>>(tmp0f, g3, be3, out_up, nullptr);

    // ================= n2e cross-attention =================
    gemm(64, sub, 512, wb[6], 512, nullptr, qkvb, 512,
         bi_n2e, nullptr, nullptr, 1.f, 0, 512, 512, 512);
    gemm(128, gn2eb, 512, wb[6] + 262144, 512, nullptr, kvb, 1024,
         bi_n2e + 512, nullptr, nullptr, 1.f, 0, 4096, 1024, 512);
    attn(qkvb, 512, kvb, 1024, kvb + 512, 1024, 256, 2048);
    avg_softmax_f<<<512, blk, 0, stream>>>(probs, stats, 256, 2048, out_w3, nullptr);
    gemm(64, attb, 512, wb[7], 512, upn2ef, nullptr, 512,
         bo_n2e, nullptr, nullptr, 1.f, 0, 512, 512, 512);

    // ================= n2n self-attention =================
    gemm(64, sub, 512, wb[8], 512, nullptr, qkvb, 1536,
         bi_n2n, nullptr, nullptr, 1.f, 0, 512, 1536, 512);
    attn(qkvb, 1536, qkvb + 512, 1536, qkvb + 1024, 1536, 256, 256);
    avg_softmax_f<<<512, blk, 0, stream>>>(probs, stats, 256, 256, out_w4, nullptr);
    gemm(64, attb, 512, wb[9], 512, tmp0f, nullptr, 512,
         bo_n2n, suf, upn2ef, 1.f, 0, 512, 512, 512);
    ln512<<<512, blk, 0, stream>>>(tmp0f, g2, be2, tmp1f, tmp1b);
    // FFN (unary)
    gemm(64, tmp1b, 512, wb[12], 512, nullptr, ffnb, 2048,
         b1fu, nullptr, nullptr, 1.f, 1, 512, 2048, 512);
    gemm(64, ffnb, 2048, wb[13], 2048, tmp0f, nullptr, 512,
         b2fu, tmp1f, nullptr, 1.f, 0, 512, 512, 2048);
    ln512<<<512, blk, 0, stream>>>(tmp0f, g3, be3, out_uu, nullptr);
}

// Round 10
// 648.245 us; speedup vs baseline: 1.1339x; 1.0562x over previous
//
#include <hip/hip_runtime.h>
#include <cstddef>

#define LN_EPS 1e-5f

typedef unsigned short u16;
typedef short short8 __attribute__((ext_vector_type(8)));
typedef float f32x4 __attribute__((ext_vector_type(4)));

__device__ __forceinline__ u16 f2bf(float f) {
    unsigned int u = __float_as_uint(f);
    u = (u + 0x7FFFu + ((u >> 16) & 1u)) >> 16;
    return (u16)u;
}
__device__ __forceinline__ float bf2f(u16 h) {
    return __uint_as_float((unsigned int)h << 16);
}

// ---------------------------------------------------------------------------
// Multi-tensor fp32 -> bf16 convert (weights + inputs), one launch.
// ---------------------------------------------------------------------------
struct CvtDesc {
    const float* src[16];
    u16* dst[16];
    int n4[16];
};
__global__ __launch_bounds__(256) void cvt_multi(CvtDesc d) {
    const int t = blockIdx.x * 256 + threadIdx.x;
    const int i = blockIdx.y;
    if (t >= d.n4[i]) return;
    const float4 v = ((const float4*)d.src[i])[t];
    ushort4 o;
    o.x = f2bf(v.x); o.y = f2bf(v.y); o.z = f2bf(v.z); o.w = f2bf(v.w);
    ((ushort4*)d.dst[i])[t] = o;
}

// ---------------------------------------------------------------------------
// bf16 MFMA NT GEMM, BMxBN tile, 4 waves (2x2), BK=32, 16x16x32 MFMA.
// LDS rows padded to 40 u16; K-loop register-prefetches the next chunk.
// C = scale*(A@B^T + bias) + res1 + res2 (+relu). Outputs fp32 and/or bf16.
// ---------------------------------------------------------------------------
template<int BM, int BN>
__global__ __launch_bounds__(256) void mfma_gemm(
    const u16* __restrict__ A, int lda,
    const u16* __restrict__ B, int ldb,
    float* __restrict__ Cf, u16* __restrict__ Ch, int ldc,
    const float* __restrict__ bias,
    const float* __restrict__ res1, const float* __restrict__ res2,
    float scale, int relu, int K)
{
    constexpr int MF = BM / 32;
    constexpr int NF = BN / 32;
    constexpr int MC = BM / 64;
    constexpr int NC = BN / 64;
    __shared__ u16 As[BM * 40];
    __shared__ u16 Bs[BN * 40];

    const int tid = threadIdx.x;
    const int wave = tid >> 6, lane = tid & 63;
    const int wm = wave >> 1, wn = wave & 1;
    const int m0 = blockIdx.y * BM, n0 = blockIdx.x * BN;

    f32x4 acc[MF][NF];
#pragma unroll
    for (int mf = 0; mf < MF; ++mf)
#pragma unroll
        for (int nf = 0; nf < NF; ++nf) acc[mf][nf] = (f32x4){0.f, 0.f, 0.f, 0.f};

    const int ar = tid >> 2, ac = (tid & 3) * 8;
    const int ml = lane & 15, kq = lane >> 4;

    short8 aN[MC], bN[NC];
#pragma unroll
    for (int c = 0; c < MC; ++c)
        aN[c] = *(const short8*)&A[(size_t)(m0 + ar + c * 64) * lda + ac];
#pragma unroll
    for (int c = 0; c < NC; ++c)
        bN[c] = *(const short8*)&B[(size_t)(n0 + ar + c * 64) * ldb + ac];

    for (int k0 = 0; k0 < K; k0 += 32) {
        short8 aS[MC], bS[NC];
#pragma unroll
        for (int c = 0; c < MC; ++c) aS[c] = aN[c];
#pragma unroll
        for (int c = 0; c < NC; ++c) bS[c] = bN[c];
        if (k0 + 32 < K) {
#pragma unroll
            for (int c = 0; c < MC; ++c)
                aN[c] = *(const short8*)&A[(size_t)(m0 + ar + c * 64) * lda + k0 + 32 + ac];
#pragma unroll
            for (int c = 0; c < NC; ++c)
                bN[c] = *(const short8*)&B[(size_t)(n0 + ar + c * 64) * ldb + k0 + 32 + ac];
        }
        __syncthreads();
#pragma unroll
        for (int c = 0; c < MC; ++c) *(short8*)&As[(ar + c * 64) * 40 + ac] = aS[c];
#pragma unroll
        for (int c = 0; c < NC; ++c) *(short8*)&Bs[(ar + c * 64) * 40 + ac] = bS[c];
        __syncthreads();

        short8 af[MF], bfr[NF];
#pragma unroll
        for (int mf = 0; mf < MF; ++mf)
            af[mf] = *(const short8*)&As[(wm * (BM / 2) + mf * 16 + ml) * 40 + kq * 8];
#pragma unroll
        for (int nf = 0; nf < NF; ++nf)
            bfr[nf] = *(const short8*)&Bs[(wn * (BN / 2) + nf * 16 + ml) * 40 + kq * 8];
#pragma unroll
        for (int mf = 0; mf < MF; ++mf)
#pragma unroll
            for (int nf = 0; nf < NF; ++nf)
                acc[mf][nf] = __builtin_amdgcn_mfma_f32_16x16x32_bf16(
                    af[mf], bfr[nf], acc[mf][nf], 0, 0, 0);
    }

    const int rq = lane >> 4;
#pragma unroll
    for (int mf = 0; mf < MF; ++mf)
#pragma unroll
        for (int nf = 0; nf < NF; ++nf) {
            const int col = n0 + wn * (BN / 2) + nf * 16 + ml;
            const float bv = bias ? bias[col] : 0.f;
#pragma unroll
            for (int r = 0; r < 4; ++r) {
                const int row = m0 + wm * (BM / 2) + mf * 16 + rq * 4 + r;
                float v = scale * (acc[mf][nf][r] + bv);
                const size_t idx = (size_t)row * ldc + col;
                if (res1) v += res1[idx];
                if (res2) v += res2[idx];
                if (relu) v = fmaxf(v, 0.f);
                if (Cf) Cf[idx] = v;
                if (Ch) Ch[idx] = f2bf(v);
            }
        }
}

// ---------------------------------------------------------------------------
// Flash attention: block = (bh, ROWS q-rows), 4 waves, S-tiles of 64.
// Per tile: scores (MFMA) -> LDS (bf16-rounded, the canonical rounding point);
// optional streamed write-only copy to global (for avg_softmax_f); per-row
// online (m,l) update; exp in LDS; O-acc rescaled by alpha; PV MFMA.
// Scores are NEVER re-read from global. Final O *= 1/l.
// ROWS=32: waves 2(m)x2(n). ROWS=16: waves 1x4. vT: [bh][64][S].
// ---------------------------------------------------------------------------
template<int ROWS, bool NEED_W>
__global__ __launch_bounds__(256) void attn_flash(
    const u16* __restrict__ Q, int ldq,
    const u16* __restrict__ Kp, int ldk,
    const u16* __restrict__ vT,
    u16* __restrict__ scores, float2* __restrict__ stats,
    u16* __restrict__ att, int L, int S)
{
    constexpr int WN   = (ROWS == 32) ? 2 : 4;
    constexpr int SPAN = 64 / WN;
    constexpr int NF   = SPAN / 16;
    constexpr int AF   = ROWS / 16;

    __shared__ u16 Qs[ROWS * 72];
    __shared__ u16 Ks[64 * 72];
    __shared__ u16 Vt[64 * 72];
    __shared__ u16 St[ROWS * 72];
    __shared__ float pm[ROWS][9];
    __shared__ float ps[ROWS][9];
    __shared__ float mrun[ROWS], lrun[ROWS], alph[ROWS];

    const int tid = threadIdx.x;
    const int wave = tid >> 6, lane = tid & 63;
    const int ml = lane & 15, rq = lane >> 4;
    const int wm = wave / WN, wn = wave % WN;
    const int i0 = blockIdx.x * ROWS;
    const int bz = blockIdx.y, bb = bz & 1, hh = bz >> 1;
    u16* Sb = NEED_W ? scores + (size_t)bz * L * S + (size_t)i0 * S : nullptr;
    const u16* Vbase = vT + (size_t)bz * 64 * S;

    if (tid < ROWS) { mrun[tid] = -1e30f; lrun[tid] = 0.f; }
    if (tid < ROWS * 8) {
        const int r = tid >> 3, dc = (tid & 7) * 8;
        *(short8*)&Qs[r * 72 + dc] =
            *(const short8*)&Q[(size_t)((i0 + r) * 2 + bb) * ldq + hh * 64 + dc];
    }
    __syncthreads();
    const short8 qf0 = *(const short8*)&Qs[(wm * 16 + ml) * 72 + rq * 8];
    const short8 qf1 = *(const short8*)&Qs[(wm * 16 + ml) * 72 + 32 + rq * 8];

    f32x4 acc[AF];
#pragma unroll
    for (int mf = 0; mf < AF; ++mf) acc[mf] = (f32x4){0.f, 0.f, 0.f, 0.f};

    for (int k0 = 0; k0 < S; k0 += 64) {
        // ---- stage K-tile [s][d] and V-tile [d][s]
#pragma unroll
        for (int c = 0; c < 2; ++c) {
            const int idx = tid + c * 256;
            const int sr = idx >> 3, dc = (idx & 7) * 8;
            *(short8*)&Ks[sr * 72 + dc] =
                *(const short8*)&Kp[(size_t)((k0 + sr) * 2 + bb) * ldk + hh * 64 + dc];
            *(short8*)&Vt[sr * 72 + dc] =
                *(const short8*)&Vbase[(size_t)sr * S + k0 + dc];
        }
        __syncthreads();
        // ---- scores tile -> St (bf16-rounded)
#pragma unroll
        for (int nf = 0; nf < NF; ++nf) {
            const int sb = wn * SPAN + nf * 16;
            const short8 kf0 = *(const short8*)&Ks[(sb + ml) * 72 + rq * 8];
            const short8 kf1 = *(const short8*)&Ks[(sb + ml) * 72 + 32 + rq * 8];
            f32x4 sc = (f32x4){0.f, 0.f, 0.f, 0.f};
            sc = __builtin_amdgcn_mfma_f32_16x16x32_bf16(qf0, kf0, sc, 0, 0, 0);
            sc = __builtin_amdgcn_mfma_f32_16x16x32_bf16(qf1, kf1, sc, 0, 0, 0);
#pragma unroll
            for (int r = 0; r < 4; ++r)
                St[(wm * 16 + rq * 4 + r) * 72 + sb + ml] = f2bf(sc[r] * 0.125f);
        }
        __syncthreads();
        // ---- stats partials (+ streamed write-only global copy)
        if (tid < ROWS * 8) {
            const int r1 = tid >> 3, q1 = tid & 7;
            const short8 v8 = *(const short8*)&St[r1 * 72 + q1 * 8];
            if (NEED_W)
                *(short8*)&Sb[(size_t)r1 * S + k0 + q1 * 8] = v8;
            float v[8], m8 = -1e30f;
#pragma unroll
            for (int j = 0; j < 8; ++j) { v[j] = bf2f((u16)v8[j]); m8 = fmaxf(m8, v[j]); }
            float s8 = 0.f;
#pragma unroll
            for (int j = 0; j < 8; ++j) s8 += __expf(v[j] - m8);
            pm[r1][q1] = m8; ps[r1][q1] = s8;
        }
        __syncthreads();
        // ---- online (m,l) update per row
        if (tid < ROWS) {
            float tm = pm[tid][0], ts = ps[tid][0];
#pragma unroll
            for (int j = 1; j < 8; ++j) {
                const float nm = fmaxf(tm, pm[tid][j]);
                ts = ts * __expf(tm - nm) + ps[tid][j] * __expf(pm[tid][j] - nm);
                tm = nm;
            }
            const float mold = mrun[tid];
            const float mnew = fmaxf(mold, tm);
            const float a = __expf(mold - mnew);
            lrun[tid] = lrun[tid] * a + ts * __expf(tm - mnew);
            mrun[tid] = mnew;
            alph[tid] = a;
        }
        __syncthreads();
        // ---- exp in place
        if (tid < ROWS * 8) {
            const int r1 = tid >> 3, q1 = tid & 7;
            const float mn = mrun[r1];
            short8 v8 = *(const short8*)&St[r1 * 72 + q1 * 8];
#pragma unroll
            for (int j = 0; j < 8; ++j)
                v8[j] = (short)f2bf(__expf(bf2f((u16)v8[j]) - mn));
            *(short8*)&St[r1 * 72 + q1 * 8] = v8;
        }
        __syncthreads();
        // ---- PV: rescale O by alpha, accumulate P-tile @ V-tile
#pragma unroll
        for (int mf = 0; mf < AF; ++mf)
#pragma unroll
            for (int rr = 0; rr < 4; ++rr)
                acc[mf][rr] *= alph[mf * 16 + rq * 4 + rr];
#pragma unroll
        for (int kc = 0; kc < 2; ++kc) {
            const short8 bfr = *(const short8*)&Vt[(wave * 16 + ml) * 72 + kc * 32 + rq * 8];
#pragma unroll
            for (int mf = 0; mf < AF; ++mf) {
                const short8 afr = *(const short8*)&St[(mf * 16 + ml) * 72 + kc * 32 + rq * 8];
                acc[mf] = __builtin_amdgcn_mfma_f32_16x16x32_bf16(afr, bfr, acc[mf], 0, 0, 0);
            }
        }
        __syncthreads();   // protect Ks/Vt/St before next tile's staging
    }

    // ---- finalize: O *= 1/l, write att (+ stats for avg_softmax_f)
#pragma unroll
    for (int mf = 0; mf < AF; ++mf)
#pragma unroll
        for (int rr = 0; rr < 4; ++rr) {
            const int row = mf * 16 + rq * 4 + rr;
            const float o = acc[mf][rr] / lrun[row];
            const int i = i0 + row;
            const int d = wave * 16 + ml;
            att[((size_t)i * 2 + bb) * 512 + hh * 64 + d] = f2bf(o);
        }
    if (NEED_W && tid < ROWS)
        stats[(size_t)bz * L + i0 + tid] = make_float2(mrun[tid], 1.0f / lrun[tid]);
}

// ---------------------------------------------------------------------------
// One-time V transpose: vT[bh][d][s] = V[(s*2+b)*ldv + h*64 + d]  (bf16).
// ---------------------------------------------------------------------------
__global__ __launch_bounds__(256) void vtrans(
    const u16* __restrict__ V, int ldv, u16* __restrict__ vT, int S)
{
    __shared__ u16 Vs[64 * 72];
    const int tid = threadIdx.x;
    const int s0 = blockIdx.x * 64;
    const int bh = blockIdx.y, b = bh & 1, h = bh >> 1;

#pragma unroll
    for (int c = 0; c < 2; ++c) {
        const int idx = tid + c * 256;
        const int sr = idx >> 3, dc = (idx & 7) * 8;
        *(short8*)&Vs[sr * 72 + dc] =
            *(const short8*)&V[(size_t)((s0 + sr) * 2 + b) * ldv + h * 64 + dc];
    }
    __syncthreads();
#pragma unroll
    for (int c = 0; c < 2; ++c) {
        const int idx = tid + c * 256;
        const int dr = idx >> 3, sc = (idx & 7) * 8;
        short8 o;
#pragma unroll
        for (int j = 0; j < 8; ++j) o[j] = (short)Vs[(sc + j) * 72 + dr];
        *(short8*)&vT[(size_t)bh * 64 * S + (size_t)dr * S + s0 + sc] = o;
    }
}

// ---------------------------------------------------------------------------
// Head-average of (stats-normalized) probs from RAW scores + second softmax
// -> fp32 out (1 or 2 copies). grid = 2*L, blockIdx.x = b*L + i.
// ---------------------------------------------------------------------------
__global__ __launch_bounds__(256) void avg_softmax_f(
    const u16* __restrict__ P, const float2* __restrict__ st, int L, int S,
    float* __restrict__ out1, float* __restrict__ out2)
{
    __shared__ float red[256];
    const int tid = threadIdx.x;
    const bool act = tid * 8 < S;
    const int b = blockIdx.x / L, i = blockIdx.x % L;
    const size_t LS = (size_t)L * S;

    float acc[8] = {};
    if (act) {
#pragma unroll
        for (int h = 0; h < 8; ++h) {
            const int bh = h * 2 + b;
            const float2 s = st[(size_t)bh * L + i];
            const short8 r8 = *(const short8*)&P[(size_t)bh * LS + (size_t)i * S + tid * 8];
#pragma unroll
            for (int j = 0; j < 8; ++j)
                acc[j] += __expf(bf2f((u16)r8[j]) - s.x) * s.y;
        }
#pragma unroll
        for (int j = 0; j < 8; ++j) acc[j] *= 0.125f;
    }
    float lmax = -1e30f;
    if (act) {
#pragma unroll
        for (int j = 0; j < 8; ++j) lmax = fmaxf(lmax, acc[j]);
    }
    red[tid] = lmax; __syncthreads();
    for (int s = 128; s; s >>= 1) {
        if (tid < s) red[tid] = fmaxf(red[tid], red[tid + s]);
        __syncthreads();
    }
    const float mx = red[0]; __syncthreads();
    float e[8];
    float ls = 0.f;
    if (act) {
#pragma unroll
        for (int j = 0; j < 8; ++j) { e[j] = __expf(acc[j] - mx); ls += e[j]; }
    }
    red[tid] = ls; __syncthreads();
    for (int s = 128; s; s >>= 1) {
        if (tid < s) red[tid] += red[tid + s];
        __syncthreads();
    }
    const float inv = 1.0f / red[0];
    if (act) {
        const size_t base = (size_t)blockIdx.x * S + tid * 8;
        float4 o0, o1;
        o0.x = e[0] * inv; o0.y = e[1] * inv; o0.z = e[2] * inv; o0.w = e[3] * inv;
        o1.x = e[4] * inv; o1.y = e[5] * inv; o1.z = e[6] * inv; o1.w = e[7] * inv;
        *(float4*)&out1[base] = o0; *(float4*)&out1[base + 4] = o1;
        if (out2) { *(float4*)&out2[base] = o0; *(float4*)&out2[base + 4] = o1; }
    }
}

// ---------------------------------------------------------------------------
// LayerNorm over rows of 512; fp32 out + optional bf16 out.
// ---------------------------------------------------------------------------
__global__ __launch_bounds__(256) void ln512(
    const float* __restrict__ X, const float* __restrict__ g,
    const float* __restrict__ be, float* __restrict__ Yf, u16* __restrict__ Yb)
{
    __shared__ float red[256];
    const int r = blockIdx.x, tid = threadIdx.x;
    const float* xr = X + (size_t)r * 512;
    const float x0 = xr[tid], x1 = xr[tid + 256];
    red[tid] = x0 + x1; __syncthreads();
    for (int st = 128; st; st >>= 1) {
        if (tid < st) red[tid] += red[tid + st];
        __syncthreads();
    }
    const float mean = red[0] * (1.0f / 512.0f); __syncthreads();
    const float d0 = x0 - mean, d1 = x1 - mean;
    red[tid] = d0 * d0 + d1 * d1; __syncthreads();
    for (int st = 128; st; st >>= 1) {
        if (tid < st) red[tid] += red[tid + st];
        __syncthreads();
    }
    const float rstd = rsqrtf(red[0] * (1.0f / 512.0f) + LN_EPS);
    const float y0 = d0 * rstd * g[tid] + be[tid];
    const float y1 = d1 * rstd * g[tid + 256] + be[tid + 256];
    float* yr = Yf + (size_t)r * 512;
    yr[tid] = y0; yr[tid + 256] = y1;
    if (Yb) {
        u16* yb = Yb + (size_t)r * 512;
        yb[tid] = f2bf(y0); yb[tid + 256] = f2bf(y1);
    }
}

// ---------------------------------------------------------------------------
// pair assembly: inverse map + gather rows to bf16.
// ---------------------------------------------------------------------------
__global__ void init_inv(int* __restrict__ inv) {
    const int i = blockIdx.x * 256 + threadIdx.x;
    if (i < 4096) inv[i] = -1;
}
__global__ void scatter_inv(int* __restrict__ inv, const int* __restrict__ ind, int n) {
    const int i = blockIdx.x * 256 + threadIdx.x;
    if (i < n) inv[ind[i]] = i;
}
__global__ void gather_rows_bf(
    u16* __restrict__ dst, const float* __restrict__ spf,
    const float* __restrict__ ep, const int* __restrict__ ind,
    const int* __restrict__ inv, int total4)
{
    const int e = blockIdx.x * 256 + threadIdx.x;
    if (e >= total4) return;
    const int row = e >> 7, c = e & 127;
    const int j = row >> 1, b = row & 1;
    const int idx = ind[j];
    const int iv = inv[idx];
    const float4* src = (iv >= 0) ? (const float4*)(spf + (size_t)(iv * 2 + b) * 512)
                                  : (const float4*)(ep + (size_t)(idx * 2 + b) * 512);
    const float4 v = src[c];
    ushort4 o; o.x = f2bf(v.x); o.y = f2bf(v.y); o.z = f2bf(v.z); o.w = f2bf(v.w);
    ((ushort4*)dst)[e] = o;
}

// ---------------------------------------------------------------------------
extern "C" void kernel_launch(void* const* d_in, const int* in_sizes, int n_in,
                              void* d_out, int out_size, void* d_ws, size_t ws_size,
                              hipStream_t stream)
{
    (void)in_sizes; (void)n_in; (void)out_size; (void)ws_size;

    const float* in_sp = (const float*)d_in[0];
    const float* in_su = (const float*)d_in[1];
    const float* in_ep = (const float*)d_in[2];
    const int* ind_pair = (const int*)d_in[3];
    const int* ind_e2e  = (const int*)d_in[4];
    const int* ind_n2e  = (const int*)d_in[5];
    const float *Wi_sa  = (const float*)d_in[6],  *bi_sa  = (const float*)d_in[7];
    const float *Wo_sa  = (const float*)d_in[8],  *bo_sa  = (const float*)d_in[9];
    const float *Wi_san = (const float*)d_in[10], *bi_san = (const float*)d_in[11];
    const float *Wo_san = (const float*)d_in[12], *bo_san = (const float*)d_in[13];
    const float *Wi_e2e = (const float*)d_in[14], *bi_e2e = (const float*)d_in[15];
    const float *Wo_e2e = (const float*)d_in[16], *bo_e2e = (const float*)d_in[17];
    const float *Wi_n2e = (const float*)d_in[18], *bi_n2e = (const float*)d_in[19];
    const float *Wo_n2e = (const float*)d_in[20], *bo_n2e = (const float*)d_in[21];
    const float *Wi_n2n = (const float*)d_in[22], *bi_n2n = (const float*)d_in[23];
    const float *Wo_n2n = (const float*)d_in[24], *bo_n2n = (const float*)d_in[25];
    const float *W1  = (const float*)d_in[26], *b1f  = (const float*)d_in[27];
    const float *W2  = (const float*)d_in[28], *b2f  = (const float*)d_in[29];
    const float *W1u = (const float*)d_in[30], *b1fu = (const float*)d_in[31];
    const float *W2u = (const float*)d_in[32], *b2fu = (const float*)d_in[33];
    const float *g1  = (const float*)d_in[34], *g1u = (const float*)d_in[35];
    const float *g2  = (const float*)d_in[36], *g3  = (const float*)d_in[37];
    const float *be1 = (const float*)d_in[38], *be1u = (const float*)d_in[39];
    const float *be2 = (const float*)d_in[40], *be3  = (const float*)d_in[41];

    float* Wf = (float*)d_ws;
    size_t of = 0;
    auto af_ = [&](size_t n) { float* p = Wf + of; of += n; return p; };
    float* spf    = af_((size_t)2048 * 512);
    float* suf    = af_((size_t)512 * 512);
    float* tmp0f  = af_((size_t)2048 * 512);
    float* tmp1f  = af_((size_t)2048 * 512);
    float* upn2ef = af_((size_t)512 * 512);
    float2* stats = (float2*)af_((size_t)2 * 16 * 1024);

    u16* Wu = (u16*)(Wf + of);
    size_t ou = 0;
    auto au_ = [&](size_t n) { u16* p = Wu + ou; ou += n; return p; };
    u16* in_spb = au_((size_t)2048 * 512);
    u16* in_sub = au_((size_t)512 * 512);
    u16* spb    = au_((size_t)2048 * 512);
    u16* sub    = au_((size_t)512 * 512);
    u16* ge2eb  = au_((size_t)4096 * 512);
    u16* gn2eb  = au_((size_t)4096 * 512);
    u16* qkvb   = au_((size_t)2048 * 1536);
    u16* kvb    = au_((size_t)4096 * 1024);
    u16* attb   = au_((size_t)2048 * 512);
    u16* tmp1b  = au_((size_t)2048 * 512);
    u16* ffnb   = au_((size_t)2048 * 2048);
    u16* vtb    = au_((size_t)16 * 64 * 2048);
    u16* probs  = au_((size_t)16 * 1024 * 2048);
    u16* wb[14];
    const int wsz[14] = {786432, 262144, 786432, 262144, 786432, 262144, 786432,
                         262144, 786432, 262144, 1048576, 1048576, 1048576, 1048576};
    for (int i = 0; i < 14; ++i) wb[i] = au_((size_t)wsz[i]);
    int* inv = (int*)(Wu + ou);

    float* out_uu = (float*)d_out;
    float* out_up = out_uu + 262144;
    float* out_w1 = out_up + 1048576;
    float* out_w2 = out_w1 + 4194304;
    float* out_w3 = out_w2 + 4194304;
    float* out_w4 = out_w3 + 1048576;

    const dim3 blk(256);

    CvtDesc cd;
    const float* wsrc[14] = {Wi_sa, Wo_sa, Wi_san, Wo_san, Wi_e2e, Wo_e2e, Wi_n2e,
                             Wo_n2e, Wi_n2n, Wo_n2n, W1, W2, W1u, W2u};
    for (int i = 0; i < 14; ++i) { cd.src[i] = wsrc[i]; cd.dst[i] = wb[i]; cd.n4[i] = wsz[i] / 4; }
    cd.src[14] = in_sp; cd.dst[14] = in_spb; cd.n4[14] = 1048576 / 4;
    cd.src[15] = in_su; cd.dst[15] = in_sub; cd.n4[15] = 262144 / 4;
    cvt_multi<<<dim3(1024, 16), blk, 0, stream>>>(cd);

    init_inv<<<16, blk, 0, stream>>>(inv);
    scatter_inv<<<4, blk, 0, stream>>>(inv, ind_pair, 1024);

    auto gemm = [&](int tile, const u16* A, int lda, const u16* B, int ldb,
                    float* Cf, u16* Ch, int ldc,
                    const float* bias, const float* r1, const float* r2,
                    float scale, int relu, int M, int N, int K) {
        if (tile == 64)
            mfma_gemm<64, 64><<<dim3(N / 64, M / 64), blk, 0, stream>>>(
                A, lda, B, ldb, Cf, Ch, ldc, bias, r1, r2, scale, relu, K);
        else
            mfma_gemm<128, 128><<<dim3(N / 128, M / 128), blk, 0, stream>>>(
                A, lda, B, ldb, Cf, Ch, ldc, bias, r1, r2, scale, relu, K);
    };
    // attention core: vtrans + flash (scores kept only if weights needed)
    auto attn = [&](const u16* Q, int ldq, const u16* Kp, int ldk,
                    const u16* V, int ldv, int L, int S, bool needW) {
        vtrans<<<dim3(S / 64, 16), blk, 0, stream>>>(V, ldv, vtb, S);
        if (L >= 1024) {
            if (needW)
                attn_flash<32, true><<<dim3(L / 32, 16), blk, 0, stream>>>(
                    Q, ldq, Kp, ldk, vtb, probs, stats, attb, L, S);
            else
                attn_flash<32, false><<<dim3(L / 32, 16), blk, 0, stream>>>(
                    Q, ldq, Kp, ldk, vtb, probs, stats, attb, L, S);
        } else {
            if (needW)
                attn_flash<16, true><<<dim3(L / 16, 16), blk, 0, stream>>>(
                    Q, ldq, Kp, ldk, vtb, probs, stats, attb, L, S);
            else
                attn_flash<16, false><<<dim3(L / 16, 16), blk, 0, stream>>>(
                    Q, ldq, Kp, ldk, vtb, probs, stats, attb, L, S);
        }
    };

    // ================= self-attention (pair) =================
    gemm(128, in_spb, 512, wb[0], 512, nullptr, qkvb, 1536,
         bi_sa, nullptr, nullptr, 1.f, 0, 2048, 1536, 512);
    attn(qkvb, 1536, qkvb + 512, 1536, qkvb + 1024, 1536, 1024, 1024, false);
    gemm(64, attb, 512, wb[1], 512, tmp0f, nullptr, 512,
         bo_sa, in_sp, nullptr, 1.f, 0, 2048, 512, 512);
    ln512<<<2048, blk, 0, stream>>>(tmp0f, g1, be1, spf, spb);

    // ================= self-attention (unary) =================
    gemm(64, in_sub, 512, wb[2], 512, nullptr, qkvb, 1536,
         bi_san, nullptr, nullptr, 1.f, 0, 512, 1536, 512);
    attn(qkvb, 1536, qkvb + 512, 1536, qkvb + 1024, 1536, 256, 256, false);
    gemm(64, attb, 512, wb[3], 512, tmp0f, nullptr, 512,
         bo_san, in_su, nullptr, 1.f, 0, 512, 512, 512);
    ln512<<<512, blk, 0, stream>>>(tmp0f, g1u, be1u, suf, sub);

    // ================= gathers =================
    gather_rows_bf<<<2048, blk, 0, stream>>>(ge2eb, spf, in_ep, ind_e2e, inv, 524288);
    gather_rows_bf<<<2048, blk, 0, stream>>>(gn2eb, spf, in_ep, ind_n2e, inv, 524288);

    // ================= e2e cross-attention =================
    gemm(64, spb, 512, wb[4], 512, nullptr, qkvb, 512,
         bi_e2e, nullptr, nullptr, 1.f, 0, 2048, 512, 512);
    gemm(128, ge2eb, 512, wb[4] + 262144, 512, nullptr, kvb, 1024,
         bi_e2e + 512, nullptr, nullptr, 1.f, 0, 4096, 1024, 512);
    attn(qkvb, 512, kvb, 1024, kvb + 512, 1024, 1024, 2048, true);
    avg_softmax_f<<<2048, blk, 0, stream>>>(probs, stats, 1024, 2048, out_w1, out_w2);
    gemm(64, attb, 512, wb[5], 512, tmp0f, nullptr, 512,
         bo_e2e, spf, nullptr, 2.f, 0, 2048, 512, 512);
    ln512<<<2048, blk, 0, stream>>>(tmp0f, g2, be2, tmp1f, tmp1b);
    // FFN (pair)
    gemm(128, tmp1b, 512, wb[10], 512, nullptr, ffnb, 2048,
         b1f, nullptr, nullptr, 1.f, 1, 2048, 2048, 512);
    gemm(64, ffnb, 2048, wb[11], 2048, tmp0f, nullptr, 512,
         b2f, tmp1f, nullptr, 1.f, 0, 2048, 512, 2048);
    ln512<<<2048, blk, 0, stream>>>(tmp0f, g3, be3, out_up, nullptr);

    // ================= n2e cross-attention =================
    gemm(64, sub, 512, wb[6], 512, nullptr, qkvb, 512,
         bi_n2e, nullptr, nullptr, 1.f, 0, 512, 512, 512);
    gemm(128, gn2eb, 512, wb[6] + 262144, 512, nullptr, kvb, 1024,
         bi_n2e + 512, nullptr, nullptr, 1.f, 0, 4096, 1024, 512);
    attn(qkvb, 512, kvb, 1024, kvb + 512, 1024, 256, 2048, true);
    avg_softmax_f<<<512, blk, 0, stream>>>(probs, stats, 256, 2048, out_w3, nullptr);
    gemm(64, attb, 512, wb[7], 512, upn2ef, nullptr, 512,
         bo_n2e, nullptr, nullptr, 1.f, 0, 512, 512, 512);

    // ================= n2n self-attention =================
    gemm(64, sub, 512, wb[8], 512, nullptr, qkvb, 1536,
         bi_n2n, nullptr, nullptr, 1.f, 0, 512, 1536, 512);
    attn(qkvb, 1536, qkvb + 512, 1536, qkvb + 1024, 1536, 256, 256, true);
    avg_softmax_f<<<512, blk, 0, stream>>>(probs, stats, 256, 256, out_w4, nullptr);
    gemm(64, attb, 512, wb[9], 512, tmp0f, nullptr, 512,
         bo_n2n, suf, upn2ef, 1.f, 0, 512, 512, 512);
    ln512<<<512, blk, 0, stream>>>(tmp0f, g2, be2, tmp1f, tmp1b);
    // FFN (unary)
    gemm(64, tmp1b, 512, wb[12], 512, nullptr, ffnb, 2048,
         b1fu, nullptr, nullptr, 1.f, 1, 512, 2048, 512);
    gemm(64, ffnb, 2048, wb[13], 2048, tmp0f, nullptr, 512,
         b2fu, tmp1f, nullptr, 1.f, 0, 512, 512, 2048);
    ln512<<<512, blk, 0, stream>>>(tmp0f, g3, be3, out_uu, nullptr);
}